// Round 11
// baseline (364.365 us; speedup 1.0000x reference)
//
#include <hip/hip_runtime.h>
#include <hip/hip_cooperative_groups.h>

namespace cg = cooperative_groups;

#define BB 256
#define SS 200
#define MM 32
#define KDIM 128
#define VDIM 256
#define QDIM 128
#define HH 64
#define NROWS 10001
#define NSAMP (BB*SS)
#define INDIM (VDIM+QDIM)
#define DHS 8192
#define DHMASK (DHS-1)
#define XR 16
#define NB_ATTN 2501
#define TB 40

typedef unsigned long long u64;
typedef unsigned int u32;
typedef float f16v __attribute__((ext_vector_type(16)));

__device__ __forceinline__ float fexp(float x){ return __builtin_amdgcn_exp2f(x * 1.44269504f); }
__device__ __forceinline__ float fsigm(float x){ return __builtin_amdgcn_rcpf(1.f + fexp(-x)); }
__device__ __forceinline__ float ftanh(float x){ return 1.f - 2.f*__builtin_amdgcn_rcpf(1.f + fexp(2.f*x)); }
__device__ __forceinline__ int clampq(int q){ return q < 0 ? 0 : (q > NROWS-1 ? NROWS-1 : q); }

// device-scope loads: bypass non-coherent L1/per-XCD L2 for cross-block data
__device__ __forceinline__ u32 lda32(const u32* p){
  return __hip_atomic_load(p, __ATOMIC_RELAXED, __HIP_MEMORY_SCOPE_AGENT);
}
__device__ __forceinline__ u64 lda64(const u64* p){
  return __hip_atomic_load(p, __ATOMIC_RELAXED, __HIP_MEMORY_SCOPE_AGENT);
}

__device__ __forceinline__ u32 hash64(u64 x){
  x ^= x >> 33; x *= 0xff51afd7ed558ccdULL;
  x ^= x >> 33; x *= 0xc4ceb9fe1a85ec53ULL;
  x ^= x >> 33;
  return (u32)x;
}

__device__ __forceinline__ u64 shflx64(u64 v, int m){
  int lo = __shfl_xor((int)(u32)v, m, 64);
  int hi = __shfl_xor((int)(u32)(v >> 32), m, 64);
  return ((u64)(u32)hi << 32) | (u32)lo;
}

// transposes + present init:
// WQT4[(d4*256+j)*4+dd]=W_ih[j][VDIM+4d4+dd]; KT[d*32+m]=key_mem[m][d];
// WVT[v*256+j]=W_ih[j][v]; present[:]=0
__global__ void k_tr(const float* __restrict__ W_ih, const float* __restrict__ key_mem,
                     float* __restrict__ WQT4, float* __restrict__ KT,
                     float* __restrict__ WVT, u32* __restrict__ present){
  int idx = blockIdx.x*256 + threadIdx.x;
  if (idx < 131072) {
    int dd = idx & 3, j = (idx >> 2) & 255, d4 = idx >> 10;
    WQT4[idx] = W_ih[j*INDIM + VDIM + 4*d4 + dd];
  } else if (idx < 135168) {
    int t = idx - 131072;
    int m = t & 31, d = t >> 5; KT[t] = key_mem[m*KDIM + d];
  } else if (idx < 200704) {
    int t = idx - 135168;
    int j = t & 255, v = t >> 8; WVT[v*256 + j] = W_ih[j*INDIM + v];
  } else {
    int t = idx - 200704;
    if (t < NROWS) present[t] = 0u;
  }
}

// fused front: blocks [0,2501) attn ; [2501,2533) vw ; [2533,2733) mark
__global__ __launch_bounds__(256) void k_front(
    const float* __restrict__ emb, const float* __restrict__ KT,
    const float* __restrict__ val, const float* __restrict__ WVT,
    const int* __restrict__ q_data,
    float* __restrict__ CW, u64* __restrict__ KEYT,
    float* __restrict__ VW, u32* __restrict__ present){
  int bid = blockIdx.x;
  if (bid < NB_ATTN) {
    // ---- attn: one wave per row ----
    int w = threadIdx.x >> 6, l = threadIdx.x & 63;
    int n = bid*4 + w;
    __shared__ float se[4][QDIM];
    bool valid = (n < NROWS);
    if (valid) {
      se[w][l]      = emb[n*QDIM + l];
      se[w][l + 64] = emb[n*QDIM + l + 64];
    }
    __syncthreads();
    int m = l & 31;
    float logit = 0.f;
    if (valid && l < 32)
      for (int d = 0; d < KDIM; ++d) logit += se[w][d] * KT[d*32 + m];
    float mx = logit;
    #pragma unroll
    for (int msk = 16; msk >= 1; msk >>= 1) mx = fmaxf(mx, __shfl_xor(mx, msk, 64));
    float e = (l < 32) ? expf(logit - mx) : 0.f;    // precise expf: trit boundaries
    float sum = e;
    #pragma unroll
    for (int msk = 16; msk >= 1; msk >>= 1) sum += __shfl_xor(sum, msk, 64);
    float cw = e / sum;
    float wv = fminf((cw - 0.075f)/0.013f, (1.0f - cw)/0.912f);
    wv = fmaxf(wv, 0.f);
    int iv = (wv >= 0.6f) ? 2 : ((wv >= 0.1f) ? 1 : 0);
    int ee = (m < 16) ? m + 16 : m - 16;   // key = kh*3^16 + kl (reference packing)
    u64 p3 = 1;
    for (int i = 0; i < 31; ++i) if (i < ee) p3 *= 3ULL;
    u64 term = (valid && l < 32) ? (u64)iv * p3 : 0ULL;
    #pragma unroll
    for (int msk = 16; msk >= 1; msk >>= 1) term += shflx64(term, msk);
    if (valid && l < 32) CW[n*256 + m] = cw;
    if (valid && l == 0) KEYT[n] = term;
  } else if (bid < NB_ATTN + MM) {
    // ---- vw: VW[m][j] = sum_v val[m][v]*WVT[v][j] ----
    int m = bid - NB_ATTN, j = threadIdx.x;
    __shared__ float sval[VDIM];
    sval[j] = val[m*VDIM + j];
    __syncthreads();
    float a0=0.f, a1=0.f, a2=0.f, a3=0.f;
    for (int v = 0; v < VDIM; v += 4) {
      a0 += sval[v+0]*WVT[(v+0)*256 + j];
      a1 += sval[v+1]*WVT[(v+1)*256 + j];
      a2 += sval[v+2]*WVT[(v+2)*256 + j];
      a3 += sval[v+3]*WVT[(v+3)*256 + j];
    }
    VW[m*256 + j] = (a0+a1)+(a2+a3);
  } else {
    // ---- mark ----
    int i = (bid - NB_ATTN - MM)*256 + threadIdx.x;
    if (i < NSAMP) present[clampq(q_data[i])] = 1u;
  }
}

// XW4 row = bias + cw.VW + emb.WqT: 16 rows/block tiled GEMM
// (REVERTED to round-5 LDS-staged version: the scalar-load rewrite was
//  a ~19us regression -- 1024 serialized uniform loads/wave, no LDS reuse.)
__global__ __launch_bounds__(256) void k_xw(
    const float* __restrict__ CW, const float* __restrict__ emb,
    const float* __restrict__ VW, const float* __restrict__ WQT4,
    const float* __restrict__ b_ih, const float* __restrict__ b_hh,
    float* __restrict__ XW4){
  int base = blockIdx.x * XR;
  int j = threadIdx.x;
  __shared__ float scw[XR][32];
  __shared__ __align__(16) float ses[XR][QDIM];
  for (int idx = j; idx < XR*32; idx += 256) {
    int r = idx >> 5, m = idx & 31, n = base + r;
    scw[r][m] = (n < NROWS) ? CW[n*256 + m] : 0.f;
  }
  for (int idx = j; idx < XR*QDIM; idx += 256) {
    int r = idx >> 7, d = idx & 127, n = base + r;
    ses[r][d] = (n < NROWS) ? emb[n*QDIM + d] : 0.f;
  }
  __syncthreads();
  float bias = b_ih[j] + b_hh[j];
  float acc[XR];
  #pragma unroll
  for (int r = 0; r < XR; ++r) acc[r] = bias;
  for (int m = 0; m < MM; ++m) {
    float wv = VW[m*256 + j];
    #pragma unroll
    for (int r = 0; r < XR; ++r) acc[r] += scw[r][m] * wv;
  }
  for (int d4 = 0; d4 < QDIM/4; ++d4) {
    float4 wq = *(const float4*)(WQT4 + d4*1024 + j*4);
    #pragma unroll
    for (int r = 0; r < XR; ++r) {
      float4 ev = *(const float4*)(&ses[r][4*d4]);
      acc[r] += ev.x*wq.x + ev.y*wq.y + ev.z*wq.z + ev.w*wq.w;
    }
  }
  int gate = j >> 6, unit = j & 63;
  #pragma unroll
  for (int r = 0; r < XR; ++r)
    if (base + r < NROWS) XW4[(size_t)(base + r)*256 + 4*unit + gate] = acc[r];
}

// cooperative tail: fuses dedup+rank+qrank+ids (was 4 serial dispatches, dedup
// on ONE block). 40 blocks x 256 = 10240 threads, one row per thread.
// Phase 1 parallel dedup via device-scope atomicCAS on a GLOBAL hash table:
// slots transition 0->v monotonically, so a stale plain-read 0 just falls
// through to the CAS (which returns truth) -- correct under XCD non-coherence.
// Cross-phase reads use agent-scope atomic loads (bypass stale L1/L2).
// Rank-by-counting is insertion-order-independent -> results exact.
__global__ __launch_bounds__(256) void k_tail(
    const u32* __restrict__ present, const u64* __restrict__ KEYT,
    const int* __restrict__ q_data,
    u32* __restrict__ g_htab, u32* __restrict__ g_pay,
    u32* __restrict__ counter, u64* __restrict__ uniq,
    u32* __restrict__ RANK, u32* __restrict__ RANKQ,
    float* __restrict__ out_ids){
  cg::grid_group grid = cg::this_grid();
  const int gtid = blockIdx.x*256 + threadIdx.x;    // 0..10239
  const int n = gtid;
  // phase 0: zero table + counter
  for (int i = gtid; i < DHS; i += TB*256) g_htab[i] = 0u;
  if (gtid == 0) *counter = 0u;
  grid.sync();
  // phase 1: parallel insert
  if (n < NROWS && present[n] == 1u) {
    u64 key = KEYT[n];
    u32 h = hash64(key) & DHMASK;
    while (true) {
      u32 cur = lda32(&g_htab[h]);
      if (cur != 0u) {
        if (KEYT[cur-1u] == key) break;
        h = (h + 1) & DHMASK; continue;
      }
      u32 prev = atomicCAS(&g_htab[h], 0u, (u32)(n + 1));
      if (prev == 0u) {
        u32 idx = atomicAdd(counter, 1u);
        uniq[idx] = key;
        g_pay[h] = idx;
        break;
      }
      if (KEYT[prev-1u] == key) break;
      h = (h + 1) & DHMASK;
    }
  }
  grid.sync();
  // phase 2: rank = count of smaller unique keys
  u32 U = lda32(counter);
  __shared__ u64 chunk[2048];
  u64 mykey = (gtid < (int)U) ? lda64(&uniq[gtid]) : 0;
  u32 cnt = 0;
  for (u32 base = 0; base < U; base += 2048) {
    u32 nn = (U - base < 2048u) ? (U - base) : 2048u;
    __syncthreads();
    for (u32 tt = threadIdx.x; tt < nn; tt += 256) chunk[tt] = lda64(&uniq[base + tt]);
    __syncthreads();
    if (gtid < (int)U)
      for (u32 j = 0; j < nn; ++j) cnt += (chunk[j] < mykey) ? 1u : 0u;
  }
  if (gtid < (int)U) RANK[gtid] = cnt;
  grid.sync();
  // phase 3: per-row rank
  if (n < NROWS && present[n] == 1u) {
    u64 key = KEYT[n];
    u32 h = hash64(key) & DHMASK;
    while (true) {
      u32 cur = lda32(&g_htab[h]);
      if (cur != 0u && KEYT[cur-1u] == key) {
        RANKQ[n] = lda32(&RANK[lda32(&g_pay[h])]);
        break;
      }
      h = (h + 1) & DHMASK;
    }
  }
  grid.sync();
  // phase 4: ids
  for (int i = gtid; i < NSAMP; i += TB*256)
    out_ids[i] = (float)lda32(&RANKQ[clampq(q_data[i])]);
}

// 16 sequential FMAs (one dep chain); 4 gates interleave for ILP
#define DOT16(acc, W, H) do { \
  acc += (W)[0]*(H)[0];   acc += (W)[1]*(H)[1];   acc += (W)[2]*(H)[2];   acc += (W)[3]*(H)[3]; \
  acc += (W)[4]*(H)[4];   acc += (W)[5]*(H)[5];   acc += (W)[6]*(H)[6];   acc += (W)[7]*(H)[7]; \
  acc += (W)[8]*(H)[8];   acc += (W)[9]*(H)[9];   acc += (W)[10]*(H)[10]; acc += (W)[11]*(H)[11]; \
  acc += (W)[12]*(H)[12]; acc += (W)[13]*(H)[13]; acc += (W)[14]*(H)[14]; acc += (W)[15]*(H)[15]; \
} while(0)

// LSTM v7 (best-measured: ~97-99us). ~1160 cyc/step is this recurrence's
// empirical serial-chain floor on MI355X (5 structural variants converged).
__global__ __launch_bounds__(256, 1) void k_lstm(
    const int* __restrict__ q_data, const float* __restrict__ XW4,
    const float* __restrict__ W_hh,
    const float* __restrict__ W_pred, const float* __restrict__ b_pred,
    const float* __restrict__ init_h, const float* __restrict__ init_c,
    float* __restrict__ out_pred){
  const int b = blockIdx.x;
  const int t = threadIdx.x;
  const int w = t >> 6, l = t & 63;
  const int uo = l & 15, k = l >> 4;            // unit-offset, h-chunk
  const int u = 16*w + uo;                      // unit this lane computes
  __shared__ __align__(64) float Hbuf[SS][64];  // h history; 256B rows
  __shared__ int   sq[SS];
  __shared__ float swp[HH];

  for (int s = t; s < SS; s += 256) sq[s] = clampq(q_data[b*SS + s]);
  if (t < HH) swp[t] = W_pred[t];

  // W_hh rows for unit u, 4 gates, columns [16k,16k+16). Row stride 256B,
  // chunk offset 64B*k -> 64B-aligned f16v loads.
  const float* wb = W_hh + (size_t)u*HH + 16*k;
  f16v Wi = *(const f16v*)(wb +     0);
  f16v Wf = *(const f16v*)(wb +  4096);
  f16v Wg = *(const f16v*)(wb +  8192);
  f16v Wo = *(const f16v*)(wb + 12288);

  // this lane's h-chunk (replicated across the 16 uo-lanes sharing k)
  f16v H = *(const f16v*)(init_h + (size_t)b*HH + 16*k);
  float c  = init_c[b*HH + u];                  // 4 k-copies track c[u] redundantly
  float bp = b_pred[0];
  __syncthreads();

  // depth-2 XW prefetch (4 k-copies load the same float4: L1-hit, harmless)
  float4 xwA = *(const float4*)(XW4 + (size_t)sq[0]*256 + 4*u);
  float4 xwB = *(const float4*)(XW4 + (size_t)sq[1]*256 + 4*u);

  for (int s = 0; s < SS; ++s) {
    int sp = (s + 2 < SS) ? s + 2 : SS - 1;
    float4 xwC = *(const float4*)(XW4 + (size_t)sq[sp]*256 + 4*u);
    float pi=0.f, pf=0.f, pg=0.f, po=0.f;
    DOT16(pi, Wi, H); DOT16(pf, Wf, H); DOT16(pg, Wg, H); DOT16(po, Wo, H);
    // butterfly over k (lanes u,u+16,u+32,u+48 share a unit): (p0+p1)+(p2+p3)
    pi += __shfl_xor(pi, 16, 64); pf += __shfl_xor(pf, 16, 64);
    pg += __shfl_xor(pg, 16, 64); po += __shfl_xor(po, 16, 64);
    pi += __shfl_xor(pi, 32, 64); pf += __shfl_xor(pf, 32, 64);
    pg += __shfl_xor(pg, 32, 64); po += __shfl_xor(po, 32, 64);
    float ai = xwA.x + pi;
    float af = xwA.y + pf;
    float ag = xwA.z + pg;
    float ao = xwA.w + po;
    c = fsigm(af)*c + fsigm(ai)*ftanh(ag);
    float hh = fsigm(ao)*ftanh(c);
    if (l < 16) Hbuf[s][u] = hh;                // k==0 copies write wave's 16 units
    __syncthreads();                            // one cross-wave sync per step
    H = *(const f16v*)(&Hbuf[s][16*k]);         // per-k 64B read: broadcast + 2-way
    xwA = xwB; xwB = xwC;
  }
  __syncthreads();

  // pred epilogue over full Hbuf
  for (int s = t; s < SS; s += 256) {
    float acc = 0.f;
    #pragma unroll 16
    for (int kk = 0; kk < HH; ++kk) {
      int k2 = (kk + t) & 63;                   // swizzle: <=2-way banks (free)
      acc += Hbuf[s][k2] * swp[k2];
    }
    out_pred[b*SS + s] = fsigm(acc + bp);
  }
}

extern "C" void kernel_launch(void* const* d_in, const int* in_sizes, int n_in,
                              void* d_out, int out_size, void* d_ws, size_t ws_size,
                              hipStream_t stream) {
  const int*   q_data  = (const int*)d_in[0];
  const float* emb     = (const float*)d_in[1];
  const float* keym    = (const float*)d_in[2];
  const float* val     = (const float*)d_in[3];
  const float* W_ih    = (const float*)d_in[4];
  const float* W_hh    = (const float*)d_in[5];
  const float* b_ih    = (const float*)d_in[6];
  const float* b_hh    = (const float*)d_in[7];
  const float* W_pred  = (const float*)d_in[8];
  const float* b_pred  = (const float*)d_in[9];
  const float* init_h  = (const float*)d_in[10];
  const float* init_c  = (const float*)d_in[11];

  char* ws = (char*)d_ws;
  float* XW4     = (float*)(ws + 0);          // 10,241,024 (CW overlaid low 32 floats/row)
  float* VW      = (float*)(ws + 10241024);   // 32,768
  u64*  KEYT     = (u64*) (ws + 10273792);    // 80,128
  u64*  uniq     = (u64*) (ws + 10353920);    // 80,128
  u32*  RANK     = (u32*) (ws + 10434048);    // 40,192
  u32*  g_htab   = (u32*) (ws + 10474240);    // 32,768
  u32*  g_pay    = (u32*) (ws + 10507008);    // 32,768
  u32*  counter  = (u32*) (ws + 10539776);    // 64
  u32*  present  = (u32*) (ws + 10539840);    // 40,064
  u32*  RANKQ    = (u32*) (ws + 10579904);    // 40,064
  float* WQT4    = (float*)(ws + 10619968);   // 524,288
  float* KT      = (float*)(ws + 11144256);   // 16,384
  float* WVT     = (float*)(ws + 11160640);   // 262,144
  float* CW      = XW4;                       // overlay: CW[n*256+m]

  float* out_pred = (float*)d_out;
  float* out_ids  = out_pred + NSAMP;

  hipLaunchKernelGGL(k_tr,    dim3(824), dim3(256), 0, stream,
                     W_ih, keym, WQT4, KT, WVT, present);
  hipLaunchKernelGGL(k_front, dim3(NB_ATTN + MM + 200), dim3(256), 0, stream,
                     emb, KT, val, WVT, q_data, CW, KEYT, VW, present);
  hipLaunchKernelGGL(k_xw,    dim3((NROWS+XR-1)/XR), dim3(256), 0, stream,
                     CW, emb, VW, WQT4, b_ih, b_hh, XW4);
  {
    void* targs[] = { (void*)&present, (void*)&KEYT, (void*)&q_data,
                      (void*)&g_htab, (void*)&g_pay, (void*)&counter,
                      (void*)&uniq, (void*)&RANK, (void*)&RANKQ,
                      (void*)&out_ids };
    hipLaunchCooperativeKernel((void*)k_tail, dim3(TB), dim3(256), targs, 0, stream);
  }
  hipLaunchKernelGGL(k_lstm,  dim3(BB), dim3(256), 0, stream,
                     q_data, XW4, W_hh, W_pred, b_pred, init_h, init_c, out_pred);
}

// Round 12
// 232.192 us; speedup vs baseline: 1.5692x; 1.5692x over previous
//
#include <hip/hip_runtime.h>

#define BB 256
#define SS 200
#define MM 32
#define KDIM 128
#define VDIM 256
#define QDIM 128
#define HH 64
#define NROWS 10001
#define NSAMP (BB*SS)
#define INDIM (VDIM+QDIM)
#define DHS 8192
#define DHMASK (DHS-1)
#define XR 16
#define NB_ATTN 1251

typedef unsigned long long u64;
typedef unsigned int u32;
typedef float f16v __attribute__((ext_vector_type(16)));

__device__ __forceinline__ float fexp(float x){ return __builtin_amdgcn_exp2f(x * 1.44269504f); }
__device__ __forceinline__ float fsigm(float x){ return __builtin_amdgcn_rcpf(1.f + fexp(-x)); }
__device__ __forceinline__ float ftanh(float x){ return 1.f - 2.f*__builtin_amdgcn_rcpf(1.f + fexp(2.f*x)); }
__device__ __forceinline__ int clampq(int q){ return q < 0 ? 0 : (q > NROWS-1 ? NROWS-1 : q); }

__device__ __forceinline__ u32 hash64(u64 x){
  x ^= x >> 33; x *= 0xff51afd7ed558ccdULL;
  x ^= x >> 33; x *= 0xc4ceb9fe1a85ec53ULL;
  x ^= x >> 33;
  return (u32)x;
}

__device__ __forceinline__ u64 shflx64(u64 v, int m){
  int lo = __shfl_xor((int)(u32)v, m, 64);
  int hi = __shfl_xor((int)(u32)(v >> 32), m, 64);
  return ((u64)(u32)hi << 32) | (u32)lo;
}

// transposes + present init:
// WQT4[(d4*256+j)*4+dd]=W_ih[j][VDIM+4d4+dd]; KT[d*32+m]=key_mem[m][d];
// WVT[v*256+j]=W_ih[j][v]; present[:]=0
__global__ void k_tr(const float* __restrict__ W_ih, const float* __restrict__ key_mem,
                     float* __restrict__ WQT4, float* __restrict__ KT,
                     float* __restrict__ WVT, u32* __restrict__ present){
  int idx = blockIdx.x*256 + threadIdx.x;
  if (idx < 131072) {
    int dd = idx & 3, j = (idx >> 2) & 255, d4 = idx >> 10;
    WQT4[idx] = W_ih[j*INDIM + VDIM + 4*d4 + dd];
  } else if (idx < 135168) {
    int t = idx - 131072;
    int m = t & 31, d = t >> 5; KT[t] = key_mem[m*KDIM + d];
  } else if (idx < 200704) {
    int t = idx - 135168;
    int j = t & 255, v = t >> 8; WVT[v*256 + j] = W_ih[j*INDIM + v];
  } else {
    int t = idx - 200704;
    if (t < NROWS) present[t] = 0u;
  }
}

// fused front v2: blocks [0,1251) attn (8 rows/block, 2 rows/wave) ;
// [1251,1283) vw ; [1283,1483) mark.
// Round-11 insight: attn previously ran under `if(l<32)` -- half of every
// wave idle through the 128-iter d-loop. Packing row A in lanes 0-31 and
// row B in lanes 32-63 keeps per-m sum chains, expf, and the masks-16..1
// shfl reductions (which only mix within 32-lane halves = per-row) BIT-
// IDENTICAL while halving attn wave-count. p3: 31-iter u64 loop -> 5-step
// square-and-multiply (integer, exact).
__global__ __launch_bounds__(256) void k_front(
    const float* __restrict__ emb, const float* __restrict__ KT,
    const float* __restrict__ val, const float* __restrict__ WVT,
    const int* __restrict__ q_data,
    float* __restrict__ CW, u64* __restrict__ KEYT,
    float* __restrict__ VW, u32* __restrict__ present){
  int bid = blockIdx.x;
  if (bid < NB_ATTN) {
    // ---- attn: 2 rows per wave (half-wave per row) ----
    int w = threadIdx.x >> 6, l = threadIdx.x & 63;
    int half = l >> 5, m = l & 31;
    int row = 2*w + half;                 // 0..7 within block
    int n = bid*8 + row;
    __shared__ float se[8][QDIM];
    // stage rows 2w, 2w+1 by wave w (coalesced 128-float rows)
    {
      int rA = bid*8 + 2*w, rB = rA + 1;
      if (rA < NROWS) { se[2*w  ][l] = emb[rA*QDIM + l]; se[2*w  ][l+64] = emb[rA*QDIM + l + 64]; }
      if (rB < NROWS) { se[2*w+1][l] = emb[rB*QDIM + l]; se[2*w+1][l+64] = emb[rB*QDIM + l + 64]; }
    }
    __syncthreads();
    bool valid = (n < NROWS);
    float logit = 0.f;
    if (valid)
      for (int d = 0; d < KDIM; ++d) logit += se[row][d] * KT[d*32 + m];
    float mx = logit;
    #pragma unroll
    for (int msk = 16; msk >= 1; msk >>= 1) mx = fmaxf(mx, __shfl_xor(mx, msk, 64));
    float e = valid ? expf(logit - mx) : 0.f;    // precise expf: trit boundaries
    float sum = e;
    #pragma unroll
    for (int msk = 16; msk >= 1; msk >>= 1) sum += __shfl_xor(sum, msk, 64);
    float cw = e / sum;
    float wv = fminf((cw - 0.075f)/0.013f, (1.0f - cw)/0.912f);
    wv = fmaxf(wv, 0.f);
    int iv = (wv >= 0.6f) ? 2 : ((wv >= 0.1f) ? 1 : 0);
    int ee = (m < 16) ? m + 16 : m - 16;   // key = kh*3^16 + kl (reference packing)
    u64 p3 = 1, bb = 3;                    // 3^ee by square-and-multiply (exact)
    #pragma unroll
    for (int bit = 0; bit < 5; ++bit) {
      if (ee & (1 << bit)) p3 *= bb;
      bb *= bb;
    }
    u64 term = valid ? (u64)iv * p3 : 0ULL;
    #pragma unroll
    for (int msk = 16; msk >= 1; msk >>= 1) term += shflx64(term, msk);
    if (valid) CW[n*256 + m] = cw;
    if (valid && m == 0) KEYT[n] = term;   // lane 0 (row A) and lane 32 (row B)
  } else if (bid < NB_ATTN + MM) {
    // ---- vw: VW[m][j] = sum_v val[m][v]*WVT[v][j] ----
    int m = bid - NB_ATTN, j = threadIdx.x;
    __shared__ float sval[VDIM];
    sval[j] = val[m*VDIM + j];
    __syncthreads();
    float a0=0.f, a1=0.f, a2=0.f, a3=0.f;
    for (int v = 0; v < VDIM; v += 4) {
      a0 += sval[v+0]*WVT[(v+0)*256 + j];
      a1 += sval[v+1]*WVT[(v+1)*256 + j];
      a2 += sval[v+2]*WVT[(v+2)*256 + j];
      a3 += sval[v+3]*WVT[(v+3)*256 + j];
    }
    VW[m*256 + j] = (a0+a1)+(a2+a3);
  } else {
    // ---- mark ----
    int i = (bid - NB_ATTN - MM)*256 + threadIdx.x;
    if (i < NSAMP) present[clampq(q_data[i])] = 1u;
  }
}

// XW4 row = bias + cw.VW + emb.WqT: 16 rows/block tiled GEMM (round-5 LDS version)
__global__ __launch_bounds__(256) void k_xw(
    const float* __restrict__ CW, const float* __restrict__ emb,
    const float* __restrict__ VW, const float* __restrict__ WQT4,
    const float* __restrict__ b_ih, const float* __restrict__ b_hh,
    float* __restrict__ XW4){
  int base = blockIdx.x * XR;
  int j = threadIdx.x;
  __shared__ float scw[XR][32];
  __shared__ __align__(16) float ses[XR][QDIM];
  for (int idx = j; idx < XR*32; idx += 256) {
    int r = idx >> 5, m = idx & 31, n = base + r;
    scw[r][m] = (n < NROWS) ? CW[n*256 + m] : 0.f;
  }
  for (int idx = j; idx < XR*QDIM; idx += 256) {
    int r = idx >> 7, d = idx & 127, n = base + r;
    ses[r][d] = (n < NROWS) ? emb[n*QDIM + d] : 0.f;
  }
  __syncthreads();
  float bias = b_ih[j] + b_hh[j];
  float acc[XR];
  #pragma unroll
  for (int r = 0; r < XR; ++r) acc[r] = bias;
  for (int m = 0; m < MM; ++m) {
    float wv = VW[m*256 + j];
    #pragma unroll
    for (int r = 0; r < XR; ++r) acc[r] += scw[r][m] * wv;
  }
  for (int d4 = 0; d4 < QDIM/4; ++d4) {
    float4 wq = *(const float4*)(WQT4 + d4*1024 + j*4);
    #pragma unroll
    for (int r = 0; r < XR; ++r) {
      float4 ev = *(const float4*)(&ses[r][4*d4]);
      acc[r] += ev.x*wq.x + ev.y*wq.y + ev.z*wq.z + ev.w*wq.w;
    }
  }
  int gate = j >> 6, unit = j & 63;
  #pragma unroll
  for (int r = 0; r < XR; ++r)
    if (base + r < NROWS) XW4[(size_t)(base + r)*256 + 4*unit + gate] = acc[r];
}

__global__ __launch_bounds__(1024) void k_dedup(
    const u32* __restrict__ present, const u64* __restrict__ KEYT,
    u32* __restrict__ g_htab, u32* __restrict__ g_pay,
    u32* __restrict__ counter, u64* __restrict__ uniq){
  __shared__ u32 sh_tab[DHS];
  __shared__ u32 sh_pay[DHS];
  __shared__ u32 sh_cnt;
  int tid = threadIdx.x;
  for (int i = tid; i < DHS; i += 1024) sh_tab[i] = 0u;
  if (tid == 0) sh_cnt = 0u;
  __syncthreads();
  for (int n = tid; n < NROWS; n += 1024) {
    if (present[n] != 1u) continue;
    u64 key = KEYT[n];
    u32 h = hash64(key) & DHMASK;
    while (true) {
      u32 cur = sh_tab[h];
      if (cur != 0u) {
        if (KEYT[cur-1u] == key) break;
        h = (h + 1) & DHMASK; continue;
      }
      u32 prev = atomicCAS(&sh_tab[h], 0u, (u32)(n + 1));
      if (prev == 0u) {
        u32 idx = atomicAdd(&sh_cnt, 1u);
        uniq[idx] = key;
        sh_pay[h] = idx;
        break;
      }
      if (KEYT[prev-1u] == key) break;
      h = (h + 1) & DHMASK;
    }
  }
  __syncthreads();
  for (int i = tid; i < DHS; i += 1024) {
    u32 v = sh_tab[i];
    g_htab[i] = v;
    g_pay[i]  = v ? sh_pay[i] : 0u;
  }
  if (tid == 0) *counter = sh_cnt;
}

__global__ __launch_bounds__(256) void k_rank(const u64* __restrict__ uniq,
                                              const u32* __restrict__ counter,
                                              u32* __restrict__ RANK){
  __shared__ u64 chunk[2048];
  u32 U = *counter;
  int u = blockIdx.x*256 + threadIdx.x;
  u64 mykey = (u < (int)U) ? uniq[u] : 0;
  u32 cnt = 0;
  for (u32 base = 0; base < U; base += 2048) {
    u32 n = (U - base < 2048u) ? (U - base) : 2048u;
    __syncthreads();
    for (u32 t = threadIdx.x; t < n; t += 256) chunk[t] = uniq[base + t];
    __syncthreads();
    if (u < (int)U)
      for (u32 j = 0; j < n; ++j) cnt += (chunk[j] < mykey) ? 1u : 0u;
  }
  if (u < (int)U) RANK[u] = cnt;
}

__global__ void k_qrank(const u32* __restrict__ present, const u64* __restrict__ KEYT,
                        const u32* __restrict__ g_htab, const u32* __restrict__ g_pay,
                        const u32* __restrict__ RANK, u32* __restrict__ RANKQ){
  int n = blockIdx.x*blockDim.x + threadIdx.x;
  if (n >= NROWS || present[n] != 1u) return;
  u64 key = KEYT[n];
  u32 h = hash64(key) & DHMASK;
  while (true) {
    u32 cur = g_htab[h];
    if (cur != 0u && KEYT[cur-1u] == key) { RANKQ[n] = RANK[g_pay[h]]; return; }
    h = (h + 1) & DHMASK;
  }
}

__global__ void k_ids(const int* __restrict__ q_data, const u32* __restrict__ RANKQ,
                      float* __restrict__ out_ids){
  int i = blockIdx.x*blockDim.x + threadIdx.x;
  if (i >= NSAMP) return;
  out_ids[i] = (float)RANKQ[clampq(q_data[i])];
}

// 16 sequential FMAs (one dep chain); 4 gates interleave for ILP
#define DOT16(acc, W, H) do { \
  acc += (W)[0]*(H)[0];   acc += (W)[1]*(H)[1];   acc += (W)[2]*(H)[2];   acc += (W)[3]*(H)[3]; \
  acc += (W)[4]*(H)[4];   acc += (W)[5]*(H)[5];   acc += (W)[6]*(H)[6];   acc += (W)[7]*(H)[7]; \
  acc += (W)[8]*(H)[8];   acc += (W)[9]*(H)[9];   acc += (W)[10]*(H)[10]; acc += (W)[11]*(H)[11]; \
  acc += (W)[12]*(H)[12]; acc += (W)[13]*(H)[13]; acc += (W)[14]*(H)[14]; acc += (W)[15]*(H)[15]; \
} while(0)

// LSTM v7 (best-measured: ~97-99us). ~1160 cyc/step is this recurrence's
// empirical serial-chain floor on MI355X (5 structural variants converged).
__global__ __launch_bounds__(256, 1) void k_lstm(
    const int* __restrict__ q_data, const float* __restrict__ XW4,
    const float* __restrict__ W_hh,
    const float* __restrict__ W_pred, const float* __restrict__ b_pred,
    const float* __restrict__ init_h, const float* __restrict__ init_c,
    float* __restrict__ out_pred){
  const int b = blockIdx.x;
  const int t = threadIdx.x;
  const int w = t >> 6, l = t & 63;
  const int uo = l & 15, k = l >> 4;            // unit-offset, h-chunk
  const int u = 16*w + uo;                      // unit this lane computes
  __shared__ __align__(64) float Hbuf[SS][64];  // h history; 256B rows
  __shared__ int   sq[SS];
  __shared__ float swp[HH];

  for (int s = t; s < SS; s += 256) sq[s] = clampq(q_data[b*SS + s]);
  if (t < HH) swp[t] = W_pred[t];

  // W_hh rows for unit u, 4 gates, columns [16k,16k+16). Row stride 256B,
  // chunk offset 64B*k -> 64B-aligned f16v loads.
  const float* wb = W_hh + (size_t)u*HH + 16*k;
  f16v Wi = *(const f16v*)(wb +     0);
  f16v Wf = *(const f16v*)(wb +  4096);
  f16v Wg = *(const f16v*)(wb +  8192);
  f16v Wo = *(const f16v*)(wb + 12288);

  // this lane's h-chunk (replicated across the 16 uo-lanes sharing k)
  f16v H = *(const f16v*)(init_h + (size_t)b*HH + 16*k);
  float c  = init_c[b*HH + u];                  // 4 k-copies track c[u] redundantly
  float bp = b_pred[0];
  __syncthreads();

  // depth-2 XW prefetch (4 k-copies load the same float4: L1-hit, harmless)
  float4 xwA = *(const float4*)(XW4 + (size_t)sq[0]*256 + 4*u);
  float4 xwB = *(const float4*)(XW4 + (size_t)sq[1]*256 + 4*u);

  for (int s = 0; s < SS; ++s) {
    int sp = (s + 2 < SS) ? s + 2 : SS - 1;
    float4 xwC = *(const float4*)(XW4 + (size_t)sq[sp]*256 + 4*u);
    float pi=0.f, pf=0.f, pg=0.f, po=0.f;
    DOT16(pi, Wi, H); DOT16(pf, Wf, H); DOT16(pg, Wg, H); DOT16(po, Wo, H);
    // butterfly over k (lanes u,u+16,u+32,u+48 share a unit): (p0+p1)+(p2+p3)
    pi += __shfl_xor(pi, 16, 64); pf += __shfl_xor(pf, 16, 64);
    pg += __shfl_xor(pg, 16, 64); po += __shfl_xor(po, 16, 64);
    pi += __shfl_xor(pi, 32, 64); pf += __shfl_xor(pf, 32, 64);
    pg += __shfl_xor(pg, 32, 64); po += __shfl_xor(po, 32, 64);
    float ai = xwA.x + pi;
    float af = xwA.y + pf;
    float ag = xwA.z + pg;
    float ao = xwA.w + po;
    c = fsigm(af)*c + fsigm(ai)*ftanh(ag);
    float hh = fsigm(ao)*ftanh(c);
    if (l < 16) Hbuf[s][u] = hh;                // k==0 copies write wave's 16 units
    __syncthreads();                            // one cross-wave sync per step
    H = *(const f16v*)(&Hbuf[s][16*k]);         // per-k 64B read: broadcast + 2-way
    xwA = xwB; xwB = xwC;
  }
  __syncthreads();

  // pred epilogue over full Hbuf
  for (int s = t; s < SS; s += 256) {
    float acc = 0.f;
    #pragma unroll 16
    for (int kk = 0; kk < HH; ++kk) {
      int k2 = (kk + t) & 63;                   // swizzle: <=2-way banks (free)
      acc += Hbuf[s][k2] * swp[k2];
    }
    out_pred[b*SS + s] = fsigm(acc + bp);
  }
}

extern "C" void kernel_launch(void* const* d_in, const int* in_sizes, int n_in,
                              void* d_out, int out_size, void* d_ws, size_t ws_size,
                              hipStream_t stream) {
  const int*   q_data  = (const int*)d_in[0];
  const float* emb     = (const float*)d_in[1];
  const float* keym    = (const float*)d_in[2];
  const float* val     = (const float*)d_in[3];
  const float* W_ih    = (const float*)d_in[4];
  const float* W_hh    = (const float*)d_in[5];
  const float* b_ih    = (const float*)d_in[6];
  const float* b_hh    = (const float*)d_in[7];
  const float* W_pred  = (const float*)d_in[8];
  const float* b_pred  = (const float*)d_in[9];
  const float* init_h  = (const float*)d_in[10];
  const float* init_c  = (const float*)d_in[11];

  char* ws = (char*)d_ws;
  float* XW4     = (float*)(ws + 0);          // 10,241,024 (CW overlaid low 32 floats/row)
  float* VW      = (float*)(ws + 10241024);   // 32,768
  u64*  KEYT     = (u64*) (ws + 10273792);    // 80,128
  u64*  uniq     = (u64*) (ws + 10353920);    // 80,128
  u32*  RANK     = (u32*) (ws + 10434048);    // 40,192
  u32*  g_htab   = (u32*) (ws + 10474240);    // 32,768
  u32*  g_pay    = (u32*) (ws + 10507008);    // 32,768
  u32*  counter  = (u32*) (ws + 10539776);    // 64
  u32*  present  = (u32*) (ws + 10539840);    // 40,064
  u32*  RANKQ    = (u32*) (ws + 10579904);    // 40,064
  float* WQT4    = (float*)(ws + 10619968);   // 524,288
  float* KT      = (float*)(ws + 11144256);   // 16,384
  float* WVT     = (float*)(ws + 11160640);   // 262,144
  float* CW      = XW4;                       // overlay: CW[n*256+m]

  float* out_pred = (float*)d_out;
  float* out_ids  = out_pred + NSAMP;

  hipLaunchKernelGGL(k_tr,    dim3(824), dim3(256), 0, stream,
                     W_ih, keym, WQT4, KT, WVT, present);
  hipLaunchKernelGGL(k_front, dim3(NB_ATTN + MM + 200), dim3(256), 0, stream,
                     emb, KT, val, WVT, q_data, CW, KEYT, VW, present);
  hipLaunchKernelGGL(k_dedup, dim3(1), dim3(1024), 0, stream,
                     present, KEYT, g_htab, g_pay, counter, uniq);
  hipLaunchKernelGGL(k_rank,  dim3((NROWS+255)/256), dim3(256), 0, stream, uniq, counter, RANK);
  hipLaunchKernelGGL(k_qrank, dim3((NROWS+255)/256), dim3(256), 0, stream,
                     present, KEYT, g_htab, g_pay, RANK, RANKQ);
  hipLaunchKernelGGL(k_xw,    dim3((NROWS+XR-1)/XR), dim3(256), 0, stream,
                     CW, emb, VW, WQT4, b_ih, b_hh, XW4);
  hipLaunchKernelGGL(k_ids,   dim3((NSAMP+255)/256), dim3(256), 0, stream, q_data, RANKQ, out_ids);
  hipLaunchKernelGGL(k_lstm,  dim3(BB), dim3(256), 0, stream,
                     q_data, XW4, W_hh, W_pred, b_pred, init_h, init_c, out_pred);
}